// Round 1
// baseline (869.933 us; speedup 1.0000x reference)
//
#include <hip/hip_runtime.h>
#include <math.h>

#define N0 1048576
#define N1 65536
#define N2 4096
#define DEG0 16
#define DEG1 10
#define D_IN 128
#define D_H 256
#define D_OUT 47

__device__ __forceinline__ float gelu_exact(float x) {
    // jax.nn.gelu(approximate=False) = 0.5*x*(1+erf(x/sqrt(2)))
    return 0.5f * x * (1.0f + erff(x * 0.70710678118654752f));
}

// ---------------------------------------------------------------------------
// Neighbor mean aggregation: out[j][:] = (1/DEG) * sum_e feat[idx[j*DEG+e]][:]
// F4 = feature dim / 4. F4 lanes cooperate on one dst row (float4 each).
// ---------------------------------------------------------------------------
template <int DEG, int F4>
__global__ __launch_bounds__(256) void agg_mean_kernel(
    const float4* __restrict__ feat, const int* __restrict__ idx,
    float4* __restrict__ out, int ndst)
{
    const int lane  = threadIdx.x % F4;
    const int local = threadIdx.x / F4;
    const int per_block = 256 / F4;
    const int j = blockIdx.x * per_block + local;
    if (j >= ndst) return;

    const int* ip = idx + (long)j * DEG;
    int srcs[DEG];
#pragma unroll
    for (int e = 0; e < DEG; ++e) srcs[e] = ip[e];

    float4 acc = make_float4(0.f, 0.f, 0.f, 0.f);
#pragma unroll
    for (int e = 0; e < DEG; ++e) {
        float4 v = feat[(long)srcs[e] * F4 + lane];
        acc.x += v.x; acc.y += v.y; acc.z += v.z; acc.w += v.w;
    }
    const float r = 1.0f / (float)DEG;
    acc.x *= r; acc.y *= r; acc.z *= r; acc.w *= r;
    out[(long)j * F4 + lane] = acc;
}

// ---------------------------------------------------------------------------
// C[M x 256] = gelu( [A1 | A2] @ [B1 ; B2]^T + bias )
// A1: M x K1 row-major (ld K1), A2: M x K2 (ld K2)
// B1: 256 x K1 row-major, B2: 256 x K2   (PyG weight layout W[out][in])
// Requires K1 == K2 here (both call sites satisfy this), BK divides K1.
// Tile: BM=128, BN=64, BK=32; 256 threads, each computes 8x4.
// ---------------------------------------------------------------------------
template <int K1, int K2>
__global__ __launch_bounds__(256) void gemm_gelu_kernel(
    const float* __restrict__ A1, const float* __restrict__ A2,
    const float* __restrict__ B1, const float* __restrict__ B2,
    const float* __restrict__ bias, float* __restrict__ C, int M)
{
    constexpr int BM = 128, BN = 64, BK = 32;
    // +4 padding keeps 16B alignment for b128 reads while breaking the
    // 8-way bank conflict on the transposed stores (down to ~2-4 way).
    __shared__ float As[BK][BM + 4];
    __shared__ float Bs[BK][BN + 4];

    const int tid = threadIdx.x;
    const int bm = blockIdx.x, bn = blockIdx.y;
    const int tx = tid & 15;        // 0..15 -> cols tx*4
    const int ty = tid >> 4;        // 0..15 -> rows ty*8
    const int r  = tid >> 3;        // 0..31 (loader row/col)
    const int c4 = (tid & 7) * 4;   // 0..28 step 4 (loader k)

    float acc[8][4];
#pragma unroll
    for (int i = 0; i < 8; ++i)
#pragma unroll
        for (int j = 0; j < 4; ++j) acc[i][j] = 0.f;

    constexpr int KT = (K1 + K2) / BK;
#pragma unroll 1
    for (int kt = 0; kt < KT; ++kt) {
        const int k0 = kt * BK;
        const float* Asrc; const float* Bsrc; int koff;
        if (k0 < K1) { Asrc = A1; Bsrc = B1; koff = k0; }
        else         { Asrc = A2; Bsrc = B2; koff = k0 - K1; }
        const int lda = (k0 < K1) ? K1 : K2;

        // A tile: BM x BK  (transposed store into As[k][row])
#pragma unroll
        for (int rr = 0; rr < 4; ++rr) {
            const int row = r + rr * 32;
            float4 v = *(const float4*)(Asrc + (long)(bm * BM + row) * lda + koff + c4);
            As[c4 + 0][row] = v.x; As[c4 + 1][row] = v.y;
            As[c4 + 2][row] = v.z; As[c4 + 3][row] = v.w;
        }
        // B tile: BN x BK (transposed store into Bs[k][n])
#pragma unroll
        for (int nn = 0; nn < 2; ++nn) {
            const int n = r + nn * 32;
            float4 v = *(const float4*)(Bsrc + (long)(bn * BN + n) * lda + koff + c4);
            Bs[c4 + 0][n] = v.x; Bs[c4 + 1][n] = v.y;
            Bs[c4 + 2][n] = v.z; Bs[c4 + 3][n] = v.w;
        }
        __syncthreads();

#pragma unroll
        for (int k = 0; k < BK; ++k) {
            float4 a0 = *(const float4*)&As[k][ty * 8];
            float4 a1 = *(const float4*)&As[k][ty * 8 + 4];
            float4 b  = *(const float4*)&Bs[k][tx * 4];
            const float av[8] = {a0.x, a0.y, a0.z, a0.w, a1.x, a1.y, a1.z, a1.w};
            const float bv[4] = {b.x, b.y, b.z, b.w};
#pragma unroll
            for (int i = 0; i < 8; ++i)
#pragma unroll
                for (int j = 0; j < 4; ++j)
                    acc[i][j] += av[i] * bv[j];
        }
        __syncthreads();
    }

    float4 b4 = *(const float4*)(bias + bn * BN + tx * 4);
    const float bb[4] = {b4.x, b4.y, b4.z, b4.w};
#pragma unroll
    for (int i = 0; i < 8; ++i) {
        const int row = bm * BM + ty * 8 + i;
        float4 o;
        o.x = gelu_exact(acc[i][0] + bb[0]);
        o.y = gelu_exact(acc[i][1] + bb[1]);
        o.z = gelu_exact(acc[i][2] + bb[2]);
        o.w = gelu_exact(acc[i][3] + bb[3]);
        *(float4*)(C + (long)row * D_H + bn * BN + tx * 4) = o;
    }
}

// ---------------------------------------------------------------------------
// out[i][n] = sum_k H[i][k] * Wo[n][k] + bo[n]   (M=4096, N=47, K=256)
// One block (64 threads) per row; row staged in LDS.
// ---------------------------------------------------------------------------
__global__ __launch_bounds__(64) void proj_kernel(
    const float* __restrict__ H, const float* __restrict__ Wo,
    const float* __restrict__ bo, float* __restrict__ out)
{
    __shared__ float hrow[D_H];
    const int i = blockIdx.x;
    ((float4*)hrow)[threadIdx.x] = ((const float4*)(H + (long)i * D_H))[threadIdx.x];
    __syncthreads();
    const int n = threadIdx.x;
    if (n < D_OUT) {
        const float* w = Wo + (long)n * D_H;
        float s = 0.f;
#pragma unroll 8
        for (int k = 0; k < D_H; ++k) s += hrow[k] * w[k];
        out[(long)i * D_OUT + n] = s + bo[n];
    }
}

extern "C" void kernel_launch(void* const* d_in, const int* in_sizes, int n_in,
                              void* d_out, int out_size, void* d_ws, size_t ws_size,
                              hipStream_t stream)
{
    const float* x        = (const float*)d_in[0];
    const int*   indices0 = (const int*)d_in[1];
    // d_in[2] = indptr0 (uniform, unused)
    const int*   indices1 = (const int*)d_in[3];
    // d_in[4] = indptr1 (uniform, unused)
    const float* Wl0 = (const float*)d_in[5];
    const float* bl0 = (const float*)d_in[6];
    const float* Wr0 = (const float*)d_in[7];
    const float* Wl1 = (const float*)d_in[8];
    const float* bl1 = (const float*)d_in[9];
    const float* Wr1 = (const float*)d_in[10];
    const float* Wo  = (const float*)d_in[11];
    const float* bo  = (const float*)d_in[12];
    float* out = (float*)d_out;

    // Workspace layout (fp32): mean0[N1*128] | h0[N1*256] | mean1[N2*256] | h1[N2*256]
    float* mean0 = (float*)d_ws;
    float* h0    = mean0 + (size_t)N1 * D_IN;
    float* mean1 = h0    + (size_t)N1 * D_H;
    float* h1    = mean1 + (size_t)N2 * D_H;

    // Layer 0: aggregate (mean over 16 neighbors, 128 feats)
    agg_mean_kernel<DEG0, D_IN / 4><<<N1 / (256 / (D_IN / 4)), 256, 0, stream>>>(
        (const float4*)x, indices0, (float4*)mean0, N1);

    // h0 = gelu([mean0 | x[:N1]] @ [Wl0;Wr0]^T + bl0)
    gemm_gelu_kernel<D_IN, D_IN><<<dim3(N1 / 128, D_H / 64), 256, 0, stream>>>(
        mean0, x, Wl0, Wr0, bl0, h0, N1);

    // Layer 1: aggregate (mean over 10 neighbors, 256 feats)
    agg_mean_kernel<DEG1, D_H / 4><<<N2 / (256 / (D_H / 4)), 256, 0, stream>>>(
        (const float4*)h0, indices1, (float4*)mean1, N2);

    // h1 = gelu([mean1 | h0[:N2]] @ [Wl1;Wr1]^T + bl1)
    gemm_gelu_kernel<D_H, D_H><<<dim3(N2 / 128, D_H / 64), 256, 0, stream>>>(
        mean1, h0, Wl1, Wr1, bl1, h1, N2);

    // out = h1 @ Wo^T + bo
    proj_kernel<<<N2, 64, 0, stream>>>(h1, Wo, bo, out);
}

// Round 2
// 809.868 us; speedup vs baseline: 1.0742x; 1.0742x over previous
//
#include <hip/hip_runtime.h>
#include <math.h>

#define N0 1048576
#define N1 65536
#define N2 4096
#define DEG0 16
#define DEG1 10
#define D_IN 128
#define D_H 256
#define D_OUT 47

typedef unsigned int uint32;
typedef __attribute__((ext_vector_type(8))) short bf16x8;
typedef __attribute__((ext_vector_type(4))) float f32x4;

__device__ __forceinline__ unsigned short f2b(float x) {
    // fp32 -> bf16 round-to-nearest-even (no NaN inputs in this workload)
    uint32 u = __float_as_uint(x);
    return (unsigned short)((u + 0x7fffu + ((u >> 16) & 1u)) >> 16);
}
__device__ __forceinline__ float b2f(unsigned short h) {
    return __uint_as_float(((uint32)h) << 16);
}
__device__ __forceinline__ float gelu_exact(float x) {
    return 0.5f * x * (1.0f + erff(x * 0.70710678118654752f));
}

// ---------------------------------------------------------------------------
// fp32 -> (hi,lo) bf16 plane split, float4-vectorized
// ---------------------------------------------------------------------------
__global__ __launch_bounds__(256) void split_f32_kernel(
    const float4* __restrict__ src, ushort4* __restrict__ hi,
    ushort4* __restrict__ lo, int n4)
{
    int i = blockIdx.x * 256 + threadIdx.x;
    if (i >= n4) return;
    float4 v = src[i];
    ushort4 h, l;
    h.x = f2b(v.x); l.x = f2b(v.x - b2f(h.x));
    h.y = f2b(v.y); l.y = f2b(v.y - b2f(h.y));
    h.z = f2b(v.z); l.z = f2b(v.z - b2f(h.z));
    h.w = f2b(v.w); l.w = f2b(v.w - b2f(h.w));
    hi[i] = h; lo[i] = l;
}

// Wo (47x256) -> zero-padded 64x256 hi/lo planes; bo -> padded 64 floats
__global__ __launch_bounds__(256) void prep_wo_kernel(
    const float4* __restrict__ Wo, const float* __restrict__ bo,
    ushort4* __restrict__ wh, ushort4* __restrict__ wl, float* __restrict__ bo_pad)
{
    int i = blockIdx.x * 256 + threadIdx.x;   // over 64*256/4 = 4096 quads
    if (i < 64 * D_H / 4) {
        int row = (i * 4) >> 8;               // /256
        float4 v = make_float4(0.f, 0.f, 0.f, 0.f);
        if (row < D_OUT) v = Wo[i];           // same linear quad index (256-wide)
        ushort4 h, l;
        h.x = f2b(v.x); l.x = f2b(v.x - b2f(h.x));
        h.y = f2b(v.y); l.y = f2b(v.y - b2f(h.y));
        h.z = f2b(v.z); l.z = f2b(v.z - b2f(h.z));
        h.w = f2b(v.w); l.w = f2b(v.w - b2f(h.w));
        wh[i] = h; wl[i] = l;
    }
    if (blockIdx.x == 0 && threadIdx.x < 64)
        bo_pad[threadIdx.x] = (threadIdx.x < D_OUT) ? bo[threadIdx.x] : 0.f;
}

// ---------------------------------------------------------------------------
// Mean aggregation, fp32 feats in -> hi/lo bf16 planes out.
// F4 lanes cooperate on one dst row (float4 each).
// ---------------------------------------------------------------------------
template <int DEG, int F4>
__global__ __launch_bounds__(256) void agg_split_f32(
    const float4* __restrict__ feat, const int* __restrict__ idx,
    ushort4* __restrict__ oh, ushort4* __restrict__ ol, int ndst)
{
    const int lane  = threadIdx.x % F4;
    const int local = threadIdx.x / F4;
    const int j = blockIdx.x * (256 / F4) + local;
    if (j >= ndst) return;

    const int* ip = idx + (long)j * DEG;
    int srcs[DEG];
#pragma unroll
    for (int e = 0; e < DEG; ++e) srcs[e] = ip[e];

    float4 acc = make_float4(0.f, 0.f, 0.f, 0.f);
#pragma unroll
    for (int e = 0; e < DEG; ++e) {
        float4 v = feat[(long)srcs[e] * F4 + lane];
        acc.x += v.x; acc.y += v.y; acc.z += v.z; acc.w += v.w;
    }
    const float r = 1.0f / (float)DEG;
    acc.x *= r; acc.y *= r; acc.z *= r; acc.w *= r;
    ushort4 h, l;
    h.x = f2b(acc.x); l.x = f2b(acc.x - b2f(h.x));
    h.y = f2b(acc.y); l.y = f2b(acc.y - b2f(h.y));
    h.z = f2b(acc.z); l.z = f2b(acc.z - b2f(h.z));
    h.w = f2b(acc.w); l.w = f2b(acc.w - b2f(h.w));
    oh[(long)j * F4 + lane] = h;
    ol[(long)j * F4 + lane] = l;
}

// Mean aggregation, hi/lo bf16 planes in -> hi/lo bf16 planes out.
template <int DEG, int F4>
__global__ __launch_bounds__(256) void agg_split_bf16(
    const ushort4* __restrict__ fh, const ushort4* __restrict__ fl,
    const int* __restrict__ idx,
    ushort4* __restrict__ oh, ushort4* __restrict__ ol, int ndst)
{
    const int lane  = threadIdx.x % F4;
    const int local = threadIdx.x / F4;
    const int j = blockIdx.x * (256 / F4) + local;
    if (j >= ndst) return;

    const int* ip = idx + (long)j * DEG;
    int srcs[DEG];
#pragma unroll
    for (int e = 0; e < DEG; ++e) srcs[e] = ip[e];

    float4 acc = make_float4(0.f, 0.f, 0.f, 0.f);
#pragma unroll
    for (int e = 0; e < DEG; ++e) {
        long o = (long)srcs[e] * F4 + lane;
        ushort4 h = fh[o], l = fl[o];
        acc.x += b2f(h.x) + b2f(l.x);
        acc.y += b2f(h.y) + b2f(l.y);
        acc.z += b2f(h.z) + b2f(l.z);
        acc.w += b2f(h.w) + b2f(l.w);
    }
    const float r = 1.0f / (float)DEG;
    acc.x *= r; acc.y *= r; acc.z *= r; acc.w *= r;
    ushort4 h, l;
    h.x = f2b(acc.x); l.x = f2b(acc.x - b2f(h.x));
    h.y = f2b(acc.y); l.y = f2b(acc.y - b2f(h.y));
    h.z = f2b(acc.z); l.z = f2b(acc.z - b2f(h.z));
    h.w = f2b(acc.w); l.w = f2b(acc.w - b2f(h.w));
    oh[(long)j * F4 + lane] = h;
    ol[(long)j * F4 + lane] = l;
}

// ---------------------------------------------------------------------------
// Split-bf16 MFMA GEMM: C[M x N] = act( [A1|A2] @ [B1|B2]^T + bias )
// All matrix operands are hi/lo bf16 plane pairs; accumulate fp32 in MFMA.
// a*b ~= ah*bh + ah*bl + al*bh  (drop al*bl, ~2^-18 relative).
// Tile: BM=128, BN=64, BK=32; 256 threads = 4 waves; wave w owns rows
// w*32..w*32+31 as 2x4 grid of 16x16 MFMA tiles.
// Verified fragment layouts (learn_hip m89/m120):
//   A: m=lane&15, k=quad*8+j   B: n=lane&15, k=quad*8+j
//   D: col=lane&15, row=quad*4+reg
// ---------------------------------------------------------------------------
template <int K1, int K2, bool GELU, bool SPLIT_OUT>
__global__ __launch_bounds__(256) void gemm_mfma(
    const unsigned short* __restrict__ A1h, const unsigned short* __restrict__ A1l,
    const unsigned short* __restrict__ A2h, const unsigned short* __restrict__ A2l,
    const unsigned short* __restrict__ B1h, const unsigned short* __restrict__ B1l,
    const unsigned short* __restrict__ B2h, const unsigned short* __restrict__ B2l,
    const float* __restrict__ bias,
    float* __restrict__ Cf, unsigned short* __restrict__ Ch, unsigned short* __restrict__ Cl,
    int ldc, int ncols)
{
    constexpr int BK = 32, LDK = 40;  // +8 pad: row stride 80B breaks conflicts
    __shared__ unsigned short sA[2][128][LDK];
    __shared__ unsigned short sB[2][64][LDK];

    const int tid  = threadIdx.x;
    const int bm   = blockIdx.x, bn = blockIdx.y;
    const int w    = tid >> 6;
    const int lane = tid & 63;
    const int quad = lane >> 4;
    const int l16  = lane & 15;

    f32x4 acc[2][4];
#pragma unroll
    for (int mt = 0; mt < 2; ++mt)
#pragma unroll
        for (int nt = 0; nt < 4; ++nt) acc[mt][nt] = (f32x4)0.f;

    constexpr int KT = (K1 + K2) / BK;
    for (int kt = 0; kt < KT; ++kt) {
        const int k0 = kt * BK;
        const unsigned short *Ah, *Al, *Bh, *Bl;
        int ka, koff;
        if (k0 < K1) { Ah = A1h; Al = A1l; Bh = B1h; Bl = B1l; ka = K1; koff = k0; }
        else         { Ah = A2h; Al = A2l; Bh = B2h; Bl = B2l; ka = (K2 ? K2 : 1); koff = k0 - K1; }

        // stage A: 128 rows x 32 k (per plane) as 512 x 16B tasks
#pragma unroll
        for (int rep = 0; rep < 2; ++rep) {
            int task = tid + rep * 256;
            int row = task >> 2, seg = task & 3;
            size_t g = (size_t)(bm * 128 + row) * ka + koff + seg * 8;
            *(uint4*)&sA[0][row][seg * 8] = *(const uint4*)(Ah + g);
            *(uint4*)&sA[1][row][seg * 8] = *(const uint4*)(Al + g);
        }
        // stage B: 64 rows x 32 k (per plane) as 256 x 16B tasks
        {
            int row = tid >> 2, seg = tid & 3;
            size_t g = (size_t)(bn * 64 + row) * ka + koff + seg * 8;
            *(uint4*)&sB[0][row][seg * 8] = *(const uint4*)(Bh + g);
            *(uint4*)&sB[1][row][seg * 8] = *(const uint4*)(Bl + g);
        }
        __syncthreads();

        bf16x8 Afh[2], Afl[2], Bfh[4], Bfl[4];
#pragma unroll
        for (int mt = 0; mt < 2; ++mt) {
            int r = w * 32 + mt * 16 + l16;
            Afh[mt] = *(const bf16x8*)&sA[0][r][quad * 8];
            Afl[mt] = *(const bf16x8*)&sA[1][r][quad * 8];
        }
#pragma unroll
        for (int nt = 0; nt < 4; ++nt) {
            int r = nt * 16 + l16;
            Bfh[nt] = *(const bf16x8*)&sB[0][r][quad * 8];
            Bfl[nt] = *(const bf16x8*)&sB[1][r][quad * 8];
        }
#pragma unroll
        for (int mt = 0; mt < 2; ++mt)
#pragma unroll
            for (int nt = 0; nt < 4; ++nt) {
                acc[mt][nt] = __builtin_amdgcn_mfma_f32_16x16x32_bf16(
                    Afl[mt], Bfh[nt], acc[mt][nt], 0, 0, 0);
                acc[mt][nt] = __builtin_amdgcn_mfma_f32_16x16x32_bf16(
                    Afh[mt], Bfl[nt], acc[mt][nt], 0, 0, 0);
                acc[mt][nt] = __builtin_amdgcn_mfma_f32_16x16x32_bf16(
                    Afh[mt], Bfh[nt], acc[mt][nt], 0, 0, 0);
            }
        __syncthreads();
    }

    // epilogue: D layout col=lane&15, row=quad*4+reg
#pragma unroll
    for (int mt = 0; mt < 2; ++mt) {
        const int row0 = bm * 128 + w * 32 + mt * 16 + quad * 4;
#pragma unroll
        for (int nt = 0; nt < 4; ++nt) {
            const int col = bn * 64 + nt * 16 + l16;
            const float bb = bias[col];
#pragma unroll
            for (int r = 0; r < 4; ++r) {
                float v = acc[mt][nt][r] + bb;
                if (GELU) v = gelu_exact(v);
                if (SPLIT_OUT) {
                    unsigned short h = f2b(v);
                    Ch[(size_t)(row0 + r) * ldc + col] = h;
                    Cl[(size_t)(row0 + r) * ldc + col] = f2b(v - b2f(h));
                } else {
                    if (col < ncols) Cf[(size_t)(row0 + r) * ldc + col] = v;
                }
            }
        }
    }
}

extern "C" void kernel_launch(void* const* d_in, const int* in_sizes, int n_in,
                              void* d_out, int out_size, void* d_ws, size_t ws_size,
                              hipStream_t stream)
{
    const float* x        = (const float*)d_in[0];
    const int*   indices0 = (const int*)d_in[1];
    const int*   indices1 = (const int*)d_in[3];
    const float* Wl0 = (const float*)d_in[5];
    const float* bl0 = (const float*)d_in[6];
    const float* Wr0 = (const float*)d_in[7];
    const float* Wl1 = (const float*)d_in[8];
    const float* bl1 = (const float*)d_in[9];
    const float* Wr1 = (const float*)d_in[10];
    const float* Wo  = (const float*)d_in[11];
    const float* bo  = (const float*)d_in[12];
    float* out = (float*)d_out;

    // Workspace: all hi/lo bf16 planes (ushort), then padded bo (float)
    unsigned short* p = (unsigned short*)d_ws;
    unsigned short* xh   = p; p += (size_t)N1 * D_IN;
    unsigned short* xl   = p; p += (size_t)N1 * D_IN;
    unsigned short* m0h  = p; p += (size_t)N1 * D_IN;
    unsigned short* m0l  = p; p += (size_t)N1 * D_IN;
    unsigned short* h0h  = p; p += (size_t)N1 * D_H;
    unsigned short* h0l  = p; p += (size_t)N1 * D_H;
    unsigned short* m1h  = p; p += (size_t)N2 * D_H;
    unsigned short* m1l  = p; p += (size_t)N2 * D_H;
    unsigned short* h1h  = p; p += (size_t)N2 * D_H;
    unsigned short* h1l  = p; p += (size_t)N2 * D_H;
    unsigned short* wl0h = p; p += 256 * 128;
    unsigned short* wl0l = p; p += 256 * 128;
    unsigned short* wr0h = p; p += 256 * 128;
    unsigned short* wr0l = p; p += 256 * 128;
    unsigned short* wl1h = p; p += 256 * 256;
    unsigned short* wl1l = p; p += 256 * 256;
    unsigned short* wr1h = p; p += 256 * 256;
    unsigned short* wr1l = p; p += 256 * 256;
    unsigned short* woh  = p; p += 64 * 256;
    unsigned short* wol  = p; p += 64 * 256;
    float* bo_pad = (float*)p;

    // --- weight / input conversions (tiny) ---
    split_f32_kernel<<<32, 256, 0, stream>>>((const float4*)Wl0, (ushort4*)wl0h, (ushort4*)wl0l, 256 * 128 / 4);
    split_f32_kernel<<<32, 256, 0, stream>>>((const float4*)Wr0, (ushort4*)wr0h, (ushort4*)wr0l, 256 * 128 / 4);
    split_f32_kernel<<<64, 256, 0, stream>>>((const float4*)Wl1, (ushort4*)wl1h, (ushort4*)wl1l, 256 * 256 / 4);
    split_f32_kernel<<<64, 256, 0, stream>>>((const float4*)Wr1, (ushort4*)wr1h, (ushort4*)wr1l, 256 * 256 / 4);
    prep_wo_kernel<<<16, 256, 0, stream>>>((const float4*)Wo, bo, (ushort4*)woh, (ushort4*)wol, bo_pad);
    split_f32_kernel<<<(N1 * D_IN / 4 + 255) / 256, 256, 0, stream>>>(
        (const float4*)x, (ushort4*)xh, (ushort4*)xl, N1 * D_IN / 4);

    // --- layer 0 ---
    agg_split_f32<DEG0, D_IN / 4><<<N1 / (256 / (D_IN / 4)), 256, 0, stream>>>(
        (const float4*)x, indices0, (ushort4*)m0h, (ushort4*)m0l, N1);

    gemm_mfma<D_IN, D_IN, true, true><<<dim3(N1 / 128, D_H / 64), 256, 0, stream>>>(
        m0h, m0l, xh, xl, wl0h, wl0l, wr0h, wr0l, bl0,
        nullptr, h0h, h0l, D_H, D_H);

    // --- layer 1 ---
    agg_split_bf16<DEG1, D_H / 4><<<N2 / (256 / (D_H / 4)), 256, 0, stream>>>(
        (const ushort4*)h0h, (const ushort4*)h0l, indices1, (ushort4*)m1h, (ushort4*)m1l, N2);

    gemm_mfma<D_H, D_H, true, true><<<dim3(N2 / 128, D_H / 64), 256, 0, stream>>>(
        m1h, m1l, h0h, h0l, wl1h, wl1l, wr1h, wr1l, bl1,
        nullptr, h1h, h1l, D_H, D_H);

    // --- final projection: N=64 padded, mask to 47 ---
    gemm_mfma<D_H, 0, false, false><<<dim3(N2 / 128, 1), 256, 0, stream>>>(
        h1h, h1l, h1h, h1l, woh, wol, woh, wol, bo_pad,
        out, nullptr, nullptr, D_OUT, D_OUT);
}